// Round 3
// baseline (300.789 us; speedup 1.0000x reference)
//
#include <hip/hip_runtime.h>

#define PFEAT 58
#define S18   18
#define ENT   324   // 18*18

// p -> (row,col,factor) tables for _assemble (FLIST=[1,3,5], offs=[0,1,4])
__device__ __constant__ unsigned char c_row[PFEAT] = {
    0,0,0,0,0,0,0,0,0,
    1,1,1,2,2,2,3,3,3,
    1,1,1,1,1,2,2,2,2,2,3,3,3,3,3,
    4,4,4,4,4,5,5,5,5,5,6,6,6,6,6,7,7,7,7,7,8,8,8,8,8};
__device__ __constant__ unsigned char c_col[PFEAT] = {
    0,1,2,3,4,5,6,7,8,
    1,2,3,1,2,3,1,2,3,
    4,5,6,7,8,4,5,6,7,8,4,5,6,7,8,
    4,5,6,7,8,4,5,6,7,8,4,5,6,7,8,4,5,6,7,8,4,5,6,7,8};
__device__ __constant__ float c_fac[PFEAT] = {
    0.5f,1,1,1,1,1,1,1,1,
    0.5f,0.5f,0.5f,0.5f,0.5f,0.5f,0.5f,0.5f,0.5f,
    1,1,1,1,1,1,1,1,1,1,1,1,1,1,1,
    0.5f,0.5f,0.5f,0.5f,0.5f,0.5f,0.5f,0.5f,0.5f,0.5f,0.5f,0.5f,0.5f,
    0.5f,0.5f,0.5f,0.5f,0.5f,0.5f,0.5f,0.5f,0.5f,0.5f,0.5f,0.5f};

// Deterministic probe: if edge_index is really int64 data read as int32,
// every high word is 0. For genuine int32 index data the sampled odd words
// are random src indices in [0,192) — all-zero over 64 samples ~ (1/192)^64.
__device__ __forceinline__ bool detect_i64(const int* __restrict__ ei) {
    const uint2* p = (const uint2*)ei;
    unsigned acc = 0u;
#pragma unroll 8
    for (int m = 0; m < 64; ++m) acc |= p[m].y;
    return acc == 0u;
}

__device__ __forceinline__ int load_idx(const int* __restrict__ ei, int pos,
                                        bool is64, int A) {
    int v = is64 ? ei[2 * pos] : ei[pos];
    v = v < 0 ? 0 : (v >= A ? A - 1 : v);   // never fault on bad decode
    return v;
}

// Zero-fill d_out (float4 vectorized).
__global__ __launch_bounds__(256) void zero_kernel(float* __restrict__ p, long long n)
{
    const long long i4 = ((long long)blockIdx.x * 256 + threadIdx.x) * 4;
    if (i4 + 3 < n) {
        *(float4*)(p + i4) = make_float4(0.f, 0.f, 0.f, 0.f);
    } else if (i4 < n) {
        for (long long i = i4; i < n; ++i) p[i] = 0.f;
    }
}

// Assemble 9x9 from feats, spin-double, rotate: sM = Rs * H18 * Rd^T.
__device__ __forceinline__ void assemble_rotate(
    const float* __restrict__ feat, const float* __restrict__ Rs,
    const float* __restrict__ Rd, float* sH9, float* sRs, float* sRd,
    float* sT, float* sM, int t, int nthreads)
{
    for (int idx = t; idx < ENT; idx += nthreads) { sRs[idx] = Rs[idx]; sRd[idx] = Rd[idx]; }
    if (t < 81) sH9[t] = 0.f;
    __syncthreads();
    if (t < PFEAT) sH9[c_row[t] * 9 + c_col[t]] = c_fac[t] * feat[t];
    __syncthreads();

    // T[pp=2i+u][q] = sum_j H9[i][j] * Rd[q][2j+u]
    for (int idx = t; idx < ENT; idx += nthreads) {
        const int pp = idx / S18, q = idx - pp * S18;
        const int i = pp >> 1, u = pp & 1;
        float acc = 0.f;
#pragma unroll
        for (int j = 0; j < 9; ++j)
            acc += sH9[i * 9 + j] * sRd[q * S18 + 2 * j + u];
        sT[idx] = acc;
    }
    __syncthreads();

    // M[p][q] = sum_pp Rs[p][pp] * T[pp][q]
    for (int idx = t; idx < ENT; idx += nthreads) {
        const int p = idx / S18, q = idx - p * S18;
        float acc = 0.f;
#pragma unroll
        for (int pp = 0; pp < S18; ++pp)
            acc += sRs[p * S18 + pp] * sT[pp * S18 + q];
        sM[idx] = acc;
    }
}

// One block per edge: assemble+rotate in LDS, scatter hop*phase into block
// (a,b) and the conjugate into (b,a) for all k. cplx=1: interleaved complex;
// cplx=0: real part only. All stores bounded by lim.
__global__ __launch_bounds__(256) void edge_kernel(
    const float* __restrict__ hop_feat,   // [E,58]
    const float* __restrict__ R,          // [A,18,18]
    const float* __restrict__ kpts,       // [K,3]
    const float* __restrict__ shift,      // [E,3]
    const int*   __restrict__ edge_index, // [2,E]
    float* __restrict__ outf,
    int E, int A, int K, int cplx, long long lim)
{
    __shared__ float sH9[81];
    __shared__ float sRs[ENT];
    __shared__ float sRd[ENT];
    __shared__ float sT[ENT];
    __shared__ float sM[ENT];
    __shared__ float sC[8];
    __shared__ float sS[8];

    const int e = blockIdx.x;
    const int t = threadIdx.x;
    const int N = A * S18;
    const long long N2 = (long long)N * N;

    const bool is64 = detect_i64(edge_index);
    const int a = load_idx(edge_index, e, is64, A);
    const int b = load_idx(edge_index, E + e, is64, A);

    if (t < K && t < 8) {
        const float sx = shift[e * 3 + 0], sy = shift[e * 3 + 1], sz = shift[e * 3 + 2];
        const float dot = kpts[t * 3 + 0] * sx + kpts[t * 3 + 1] * sy + kpts[t * 3 + 2] * sz;
        const float ang = -6.28318530717958647692f * dot;
        float sv, cv;
        sincosf(ang, &sv, &cv);
        sC[t] = cv; sS[t] = sv;
    }

    assemble_rotate(hop_feat + (size_t)e * PFEAT,
                    R + (size_t)a * ENT, R + (size_t)b * ENT,
                    sH9, sRs, sRd, sT, sM, t, 256);
    __syncthreads();

    const int total = K * ENT;
    for (int idx = t; idx < total; idx += 256) {
        const int k = idx / ENT, r = idx - k * ENT;
        const int i = r / S18, j = r - i * S18;
        const float v = sM[r];
        const float re = v * sC[k];
        const float im = v * sS[k];
        const long long I = (long long)a * S18 + i;
        const long long J = (long long)b * S18 + j;
        const long long p1 = k * N2 + I * N + J;   // (a,b) element
        const long long p2 = k * N2 + J * N + I;   // (b,a) element
        if (cplx) {
            if (2 * p1 + 1 < lim) {
                atomicAdd(&outf[2 * p1],     re);
                atomicAdd(&outf[2 * p1 + 1], im);
            }
            if (2 * p2 + 1 < lim) {
                atomicAdd(&outf[2 * p2],     re);
                atomicAdd(&outf[2 * p2 + 1], -im);
            }
        } else {
            if (p1 < lim) atomicAdd(&outf[p1], re);
            if (p2 < lim) atomicAdd(&outf[p2], re);
        }
    }
}

// One block per atom: add O + O^T onto the (real part of the) diagonal block
// for every k. Runs after edge_kernel on the stream -> plain RMW safe.
__global__ __launch_bounds__(128) void onsite_kernel(
    const float* __restrict__ ons_feat,   // [A,58]
    const float* __restrict__ R,          // [A,18,18]
    float* __restrict__ outf,
    int A, int K, int cplx, long long lim)
{
    __shared__ float sH9[81];
    __shared__ float sRs[ENT];
    __shared__ float sRd[ENT];
    __shared__ float sT[ENT];
    __shared__ float sM[ENT];

    const int a = blockIdx.x;
    const int t = threadIdx.x;
    const int N = A * S18;
    const long long N2 = (long long)N * N;

    assemble_rotate(ons_feat + (size_t)a * PFEAT,
                    R + (size_t)a * ENT, R + (size_t)a * ENT,
                    sH9, sRs, sRd, sT, sM, t, 128);
    __syncthreads();

    for (int idx = t; idx < ENT; idx += 128) {
        const int i = idx / S18, j = idx - (idx / S18) * S18;
        const float v = sM[i * S18 + j] + sM[j * S18 + i];
        const long long I = (long long)a * S18 + i;
        const long long J = (long long)a * S18 + j;
        for (int k = 0; k < K; ++k) {
            const long long p1 = k * N2 + I * N + J;
            const long long off = cplx ? 2 * p1 : p1;
            if (off < lim) outf[off] += v;
        }
    }
}

extern "C" void kernel_launch(void* const* d_in, const int* in_sizes, int n_in,
                              void* d_out, int out_size, void* d_ws, size_t ws_size,
                              hipStream_t stream) {
    const float* hop_feat   = (const float*)d_in[0];
    const float* ons_feat   = (const float*)d_in[1];
    const float* R          = (const float*)d_in[2];
    const float* kpts       = (const float*)d_in[3];
    const float* shift      = (const float*)d_in[4];
    const int*   edge_index = (const int*)d_in[5];

    const int E = in_sizes[0] / PFEAT;   // 3072
    const int A = in_sizes[1] / PFEAT;   // 192
    const int K = in_sizes[3] / 3;       // 4

    const long long N  = (long long)A * S18;
    const long long n_real = (long long)K * N * N;     // real-part element count
    const long long lim = (long long)out_size;         // floats we may touch
    const int cplx = (lim >= 2 * n_real) ? 1 : 0;

    float* outf = (float*)d_out;

    const long long n4 = (lim + 3) / 4;
    const int zgrid = (int)((n4 + 255) / 256);
    zero_kernel<<<zgrid, 256, 0, stream>>>(outf, lim);

    edge_kernel<<<E, 256, 0, stream>>>(hop_feat, R, kpts, shift, edge_index,
                                       outf, E, A, K, cplx, lim);
    onsite_kernel<<<A, 128, 0, stream>>>(ons_feat, R, outf, A, K, cplx, lim);
}